// Round 2
// baseline (232.421 us; speedup 1.0000x reference)
//
#include <hip/hip_runtime.h>

#define B_ 4
#define T_ 4096
#define D_ 1024
#define H_ 8
#define NC_ 64          // chunks per sequence
#define CL_ 64          // chunk length (T_/NC_)
#define M_ (B_*T_)      // 16384 flat rows

typedef unsigned short u16;
typedef unsigned int u32;
typedef __attribute__((ext_vector_type(8))) short s16x8;
typedef __attribute__((ext_vector_type(4))) float f32x4;

__device__ __forceinline__ float bf2f(u16 u){
  union { u32 i; float f; } v; v.i = ((u32)u) << 16; return v.f;
}
__device__ __forceinline__ u16 f2bf(float f){
  union { float f; u32 i; } v; v.f = f;
  u32 i = v.i;
  return (u16)((i + 0x7FFFu + ((i >> 16) & 1u)) >> 16);
}
__device__ __forceinline__ float sigf(float z){
  return __fdividef(1.0f, 1.0f + __expf(-z));
}

// ---------------------------------------------------------------- K0
// wt[(m*8+h)][e][k] = bf16(w_m[h][k][e])  (MFMA B-frags read 8 contiguous k)
__global__ __launch_bounds__(256) void k0_transpose(const float* __restrict__ w_in,
                                                    const float* __restrict__ w_a,
                                                    u16* __restrict__ wt){
  __shared__ float ls[128][132];
  const int blk = blockIdx.x;                       // m*8+h
  const float* src = (blk < 8 ? w_in : w_a) + (size_t)(blk & 7) * 128 * 128;
  u16* dst = wt + (size_t)blk * 128 * 128;
  const int tid = threadIdx.x;
  const int r0 = tid >> 5;          // 0..7
  const int c0 = (tid & 31) * 4;    // 0..124
  #pragma unroll
  for (int it = 0; it < 16; ++it){
    int r = r0 + it * 8;
    *(float4*)(&ls[r][c0]) = *(const float4*)(src + r * 128 + c0);
  }
  __syncthreads();
  #pragma unroll
  for (int it = 0; it < 16; ++it){
    int e = r0 + it * 8;            // output row (feature e)
    ushort4 u;
    u.x = f2bf(ls[c0 + 0][e]);
    u.y = f2bf(ls[c0 + 1][e]);
    u.z = f2bf(ls[c0 + 2][e]);
    u.w = f2bf(ls[c0 + 3][e]);
    *(ushort4*)(dst + e * 128 + c0) = u;
  }
}

// ------------------------------------------------- K1: MFMA GEMM + gates
// grid = 1024: h = blk&7, m-block = blk>>3 (128 rows each).
// C1 = X@W_in, C2 = X@W_a (128x128 each), then
// log_a = -8*softplus(ap)*sigmoid(C2) -> bf16 ws; b = sqrt(1-exp(2*log_a))*sigmoid(C1)*x -> fp32 into y-region.
__global__ __launch_bounds__(256) void k1_gemm(const float* __restrict__ x,
                                               const float* __restrict__ a_param,
                                               const u16* __restrict__ wt,
                                               u16* __restrict__ la_out,
                                               float* __restrict__ b_out){
  __shared__ u16 Xs[128][136];     // bf16 tile; +8 pad keeps 16B align
  __shared__ float aspS[128];
  const int blk = blockIdx.x;
  const int h = blk & 7;
  const int mbase = (blk >> 3) * 128;
  const int tid = threadIdx.x;

  {
    const int r0 = tid >> 5;          // 0..7
    const int c0 = (tid & 31) * 4;    // 0..124
    #pragma unroll
    for (int it = 0; it < 16; ++it){
      int r = r0 + it * 8;
      float4 v = *(const float4*)(x + (size_t)(mbase + r) * D_ + h * 128 + c0);
      ushort4 u;
      u.x = f2bf(v.x); u.y = f2bf(v.y); u.z = f2bf(v.z); u.w = f2bf(v.w);
      *(ushort4*)(&Xs[r][c0]) = u;
    }
  }
  if (tid < 128){
    float ap = a_param[h * 128 + tid];
    aspS[tid] = 8.0f * log1pf(__expf(ap));   // C * softplus(a_param)
  }
  __syncthreads();

  const int wv = tid >> 6, lane = tid & 63;
  const int q = lane >> 4, l = lane & 15;

  f32x4 accX[2][8], accA[2][8];
  #pragma unroll
  for (int mt = 0; mt < 2; ++mt)
    #pragma unroll
    for (int nt = 0; nt < 8; ++nt){ accX[mt][nt] = (f32x4)0.0f; accA[mt][nt] = (f32x4)0.0f; }

  const u16* wbase = wt + ((size_t)h * 128 + l) * 128;   // row e = h-block base + l
  #pragma unroll
  for (int kb = 0; kb < 4; ++kb){
    const int ko = kb * 32 + q * 8;
    s16x8 a0 = *(const s16x8*)(&Xs[wv * 32 + l][ko]);
    s16x8 a1 = *(const s16x8*)(&Xs[wv * 32 + 16 + l][ko]);
    #pragma unroll
    for (int nt = 0; nt < 8; ++nt){
      s16x8 bi = *(const s16x8*)(wbase + nt * 16 * 128 + ko);
      s16x8 ba = *(const s16x8*)(wbase + nt * 16 * 128 + ko + 8 * 128 * 128);
      accX[0][nt] = __builtin_amdgcn_mfma_f32_16x16x32_bf16(a0, bi, accX[0][nt], 0, 0, 0);
      accX[1][nt] = __builtin_amdgcn_mfma_f32_16x16x32_bf16(a1, bi, accX[1][nt], 0, 0, 0);
      accA[0][nt] = __builtin_amdgcn_mfma_f32_16x16x32_bf16(a0, ba, accA[0][nt], 0, 0, 0);
      accA[1][nt] = __builtin_amdgcn_mfma_f32_16x16x32_bf16(a1, ba, accA[1][nt], 0, 0, 0);
    }
  }

  // epilogue: C/D layout col=lane&15, row=(lane>>4)*4+reg  [m89/m91 verified]
  #pragma unroll
  for (int mt = 0; mt < 2; ++mt){
    #pragma unroll
    for (int nt = 0; nt < 8; ++nt){
      #pragma unroll
      for (int r = 0; r < 4; ++r){
        const int row = wv * 32 + mt * 16 + q * 4 + r;
        const int e = nt * 16 + l;
        size_t gi = (size_t)(mbase + row) * D_ + h * 128 + e;
        float gx = sigf(accX[mt][nt][r]);
        float ga = sigf(accA[mt][nt][r]);
        float la = -aspS[e] * ga;                       // log_a in (-0.105, 0)
        float mult = sqrtf(fmaxf(1.0f - __expf(2.0f * la), 0.0f));
        float xv = x[gi];                               // fp32 x (L1/L2-hot)
        la_out[gi] = f2bf(la);
        b_out[gi] = mult * gx * xv;
      }
    }
  }
}

// ----------------------------------------------- K2a: per-chunk carries
// grid = B*NC*4 blocks x 256 thr; thread = one channel d of one (b,chunk).
__global__ __launch_bounds__(256) void k2a_carry(const u16* __restrict__ la_arr,
                                                 const float* __restrict__ bv_arr,
                                                 float* __restrict__ carA,
                                                 float* __restrict__ carY){
  const int blk = blockIdx.x;
  const int dg = blk & 3;
  const int c = (blk >> 2) & (NC_ - 1);
  const int b = blk >> 8;
  const int d = dg * 256 + threadIdx.x;
  size_t base = ((size_t)b * T_ + c * CL_) * D_ + d;
  float A = 1.0f, Y = 0.0f;
  #pragma unroll 8
  for (int t = 0; t < CL_; ++t){
    size_t idx = base + (size_t)t * D_;
    float a = __expf(bf2f(la_arr[idx]));
    float bb = bv_arr[idx];
    Y = fmaf(a, Y, bb);
    A *= a;
  }
  int ci = (b * NC_ + c) * D_ + d;
  carA[ci] = A;
  carY[ci] = Y;
}

// ------------------------------------- K3: scan carries, emit h_last
__global__ __launch_bounds__(256) void k3_scan_carries(const float* __restrict__ carA,
                                                       const float* __restrict__ carY,
                                                       float* __restrict__ hin,
                                                       float* __restrict__ hlast){
  const int g = blockIdx.x * 256 + threadIdx.x;   // 0..4095 channels
  const int b = g >> 10, d = g & 1023;
  float h = 0.0f;
  #pragma unroll 16
  for (int c = 0; c < NC_; ++c){
    int ci = (b * NC_ + c) * D_ + d;
    float A = carA[ci], Y = carY[ci];
    hin[ci] = h;                 // exclusive prefix: state entering chunk c
    h = fmaf(A, h, Y);
  }
  hlast[b * D_ + d] = h;         // final state == y[:, -1, :]
}

// --------------------------------- K2b: final scan with chunk prefix
// bv_arr aliases y_out (b stored in the output region); per element the read
// happens before the write in the same thread -> safe in-place.
__global__ __launch_bounds__(256) void k2b_scan(const u16* __restrict__ la_arr,
                                                const float* __restrict__ hin,
                                                float* __restrict__ y_out){
  const int blk = blockIdx.x;
  const int dg = blk & 3;
  const int c = (blk >> 2) & (NC_ - 1);
  const int b = blk >> 8;
  const int d = dg * 256 + threadIdx.x;
  size_t base = ((size_t)b * T_ + c * CL_) * D_ + d;
  float y = hin[(b * NC_ + c) * D_ + d];
  #pragma unroll 8
  for (int t = 0; t < CL_; ++t){
    size_t idx = base + (size_t)t * D_;
    float a = __expf(bf2f(la_arr[idx]));
    float bb = y_out[idx];
    y = fmaf(a, y, bb);
    y_out[idx] = y;
  }
}

extern "C" void kernel_launch(void* const* d_in, const int* in_sizes, int n_in,
                              void* d_out, int out_size, void* d_ws, size_t ws_size,
                              hipStream_t stream) {
  const float* x    = (const float*)d_in[0];
  const float* ap   = (const float*)d_in[1];
  const float* w_in = (const float*)d_in[2];
  const float* w_a  = (const float*)d_in[3];
  float* y = (float*)d_out;                       // 16,777,216 floats
  float* hlast = y + (size_t)B_ * T_ * D_;        // + 4096 floats

  char* ws = (char*)d_ws;
  u16*   ws_la = (u16*)(ws);                      // 33,554,432 B
  float* carA  = (float*)(ws + 33554432);         //  1,048,576 B
  float* carY  = (float*)(ws + 34603008);         //  1,048,576 B
  float* hin   = (float*)(ws + 35651584);         //  1,048,576 B
  u16*   wt    = (u16*)(ws + 36700160);           //    524,288 B   (total ~35.5 MB)

  k0_transpose<<<16, 256, 0, stream>>>(w_in, w_a, wt);
  k1_gemm<<<(M_ / 128) * H_, 256, 0, stream>>>(x, ap, wt, ws_la, y);
  k2a_carry<<<B_ * NC_ * 4, 256, 0, stream>>>(ws_la, y, carA, carY);
  k3_scan_carries<<<16, 256, 0, stream>>>(carA, carY, hin, hlast);
  k2b_scan<<<B_ * NC_ * 4, 256, 0, stream>>>(ws_la, hin, y);
}

// Round 3
// 218.949 us; speedup vs baseline: 1.0615x; 1.0615x over previous
//
#include <hip/hip_runtime.h>

#define B_ 4
#define T_ 4096
#define D_ 1024
#define H_ 8
#define CL2_ 16            // scan chunk length
#define NC2_ (T_/CL2_)     // 256 chunks per sequence
#define M_ (B_*T_)         // 16384 flat rows

typedef unsigned short u16;
typedef unsigned int u32;
typedef __attribute__((ext_vector_type(8))) short s16x8;
typedef __attribute__((ext_vector_type(4))) float f32x4;

__device__ __forceinline__ float bf2f(u16 u){
  union { u32 i; float f; } v; v.i = ((u32)u) << 16; return v.f;
}
__device__ __forceinline__ u16 f2bf(float f){
  union { float f; u32 i; } v; v.f = f;
  u32 i = v.i;
  return (u16)((i + 0x7FFFu + ((i >> 16) & 1u)) >> 16);
}
__device__ __forceinline__ float sigf(float z){
  return __fdividef(1.0f, 1.0f + __expf(-z));
}

// ---------------------------------------------------------------- K0
// wt[(mat*8+h)][e][k] = bf16(w_mat[h][k][e])
__global__ __launch_bounds__(256) void k0_transpose(const float* __restrict__ w_in,
                                                    const float* __restrict__ w_a,
                                                    u16* __restrict__ wt){
  __shared__ float ls[128][132];
  const int blk = blockIdx.x;                       // mat*8+h
  const float* src = (blk < 8 ? w_in : w_a) + (size_t)(blk & 7) * 128 * 128;
  u16* dst = wt + (size_t)blk * 128 * 128;
  const int tid = threadIdx.x;
  const int r0 = tid >> 5;          // 0..7
  const int c0 = (tid & 31) * 4;    // 0..124
  #pragma unroll
  for (int it = 0; it < 16; ++it){
    int r = r0 + it * 8;
    *(float4*)(&ls[r][c0]) = *(const float4*)(src + r * 128 + c0);
  }
  __syncthreads();
  #pragma unroll
  for (int it = 0; it < 16; ++it){
    int e = r0 + it * 8;
    ushort4 u;
    u.x = f2bf(ls[c0 + 0][e]);
    u.y = f2bf(ls[c0 + 1][e]);
    u.z = f2bf(ls[c0 + 2][e]);
    u.w = f2bf(ls[c0 + 3][e]);
    *(ushort4*)(dst + e * 128 + c0) = u;
  }
}

// ------------------------------------------------- K1: MFMA GEMM + gates + chunk carries
// grid = 2048: h = blk&7, eh = (blk>>3)&1 (e-half), mb = blk>>4 (128-row tile).
// Per wave: 32 rows x 64 e x both matrices -> 16 f32x4 acc (64 VGPRs).
// Epilogue: pack (bf16 la | bf16 b << 16) -> LDS (aliased over Xs) -> coalesced
// uint4 stores; then per-16-step chunk carries (A=exp(sum la), Y) to carA/carY.
__global__ __launch_bounds__(256, 3) void k1_gemm(const float* __restrict__ x,
                                                  const float* __restrict__ a_param,
                                                  const u16* __restrict__ wt,
                                                  u32* pack,
                                                  float* __restrict__ carA,
                                                  float* __restrict__ carY){
  __shared__ __align__(16) char smem[128 * 74 * 4];   // 37,888 B
  u16 (*Xs)[132] = (u16 (*)[132])smem;                 // 33,792 B (K-loop phase)
  u32 (*pS)[74]  = (u32 (*)[74])smem;                  // 37,888 B (epilogue phase)
  __shared__ float aspS[64];

  const int blk = blockIdx.x;
  const int h = blk & 7;
  const int eh = (blk >> 3) & 1;
  const int mbase = (blk >> 4) * 128;
  const int tid = threadIdx.x;

  // stage X tile (full K=128 of this head), fp32 -> bf16
  {
    const int r0 = tid >> 5;          // 0..7
    const int c0 = (tid & 31) * 4;    // 0..124
    #pragma unroll
    for (int it = 0; it < 16; ++it){
      int r = r0 + it * 8;
      float4 v = *(const float4*)(x + (size_t)(mbase + r) * D_ + h * 128 + c0);
      ushort4 u;
      u.x = f2bf(v.x); u.y = f2bf(v.y); u.z = f2bf(v.z); u.w = f2bf(v.w);
      *(ushort4*)(&Xs[r][c0]) = u;
    }
  }
  if (tid < 64){
    float ap = a_param[h * 128 + eh * 64 + tid];
    aspS[tid] = 8.0f * log1pf(__expf(ap));   // C * softplus(a_param)
  }
  __syncthreads();

  const int wv = tid >> 6, lane = tid & 63;
  const int q = lane >> 4, l = lane & 15;

  f32x4 accX[2][4], accA[2][4];
  #pragma unroll
  for (int mt = 0; mt < 2; ++mt)
    #pragma unroll
    for (int nt = 0; nt < 4; ++nt){ accX[mt][nt] = (f32x4)0.0f; accA[mt][nt] = (f32x4)0.0f; }

  // B-frag rows: e = eh*64 + nt*16 + l ; second matrix at +8*128*128 elements.
  const u16* wbase = wt + ((size_t)(h * 128 + eh * 64 + l)) * 128;
  #pragma unroll
  for (int kb = 0; kb < 4; ++kb){
    const int ko = kb * 32 + q * 8;
    s16x8 a0 = *(const s16x8*)(&Xs[wv * 32 + l][ko]);
    s16x8 a1 = *(const s16x8*)(&Xs[wv * 32 + 16 + l][ko]);
    #pragma unroll
    for (int nt = 0; nt < 4; ++nt){
      s16x8 bi = *(const s16x8*)(wbase + nt * 16 * 128 + ko);
      s16x8 ba = *(const s16x8*)(wbase + nt * 16 * 128 + ko + 8 * 128 * 128);
      accX[0][nt] = __builtin_amdgcn_mfma_f32_16x16x32_bf16(a0, bi, accX[0][nt], 0, 0, 0);
      accX[1][nt] = __builtin_amdgcn_mfma_f32_16x16x32_bf16(a1, bi, accX[1][nt], 0, 0, 0);
      accA[0][nt] = __builtin_amdgcn_mfma_f32_16x16x32_bf16(a0, ba, accA[0][nt], 0, 0, 0);
      accA[1][nt] = __builtin_amdgcn_mfma_f32_16x16x32_bf16(a1, ba, accA[1][nt], 0, 0, 0);
    }
  }
  __syncthreads();   // Xs dead; smem becomes pS

  // E1: gates -> packed (la, b) into LDS.  C/D layout: col=lane&15, row=quad*4+reg.
  #pragma unroll
  for (int mt = 0; mt < 2; ++mt){
    #pragma unroll
    for (int nt = 0; nt < 4; ++nt){
      #pragma unroll
      for (int r = 0; r < 4; ++r){
        const int row = wv * 32 + mt * 16 + q * 4 + r;
        const int el = nt * 16 + l;
        float gx = sigf(accX[mt][nt][r]);
        float ga = sigf(accA[mt][nt][r]);
        float la = -aspS[el] * ga;                        // (-0.105, 0)
        float mult = sqrtf(fmaxf(1.0f - __expf(2.0f * la), 0.0f));
        float xv = x[(size_t)(mbase + row) * D_ + h * 128 + eh * 64 + el];
        float bv = mult * gx * xv;
        pS[row][el] = (u32)f2bf(la) | ((u32)f2bf(bv) << 16);
      }
    }
  }
  __syncthreads();

  // E2: coalesced packed stores (4 rows x 256 B per wave instruction)
  {
    const int r0 = tid >> 4;          // 0..15
    const int e4 = (tid & 15) * 4;    // 0..60
    const size_t gbase = (size_t)h * 128 + eh * 64 + e4;
    #pragma unroll
    for (int it = 0; it < 8; ++it){
      int row = r0 + it * 16;
      uint4 v = *(uint4*)(&pS[row][e4]);
      *(uint4*)(&pack[(size_t)(mbase + row) * D_ + gbase]) = v;
    }
  }

  // E3: per-16-step chunk carries. 8 sub-chunks of 16 rows; 4 thread-slots/el.
  {
    const int el = tid & 63;
    const int s0 = tid >> 6;          // 0..3
    const int batch = mbase / T_;
    const int c0 = (mbase % T_) / CL2_;
    const int d = h * 128 + eh * 64 + el;
    #pragma unroll
    for (int ss = s0; ss < 8; ss += 4){
      float S = 0.0f, Y = 0.0f;
      #pragma unroll
      for (int j = 0; j < CL2_; ++j){
        u32 w = pS[ss * CL2_ + j][el];
        float la = bf2f((u16)(w & 0xFFFFu));
        float bb = bf2f((u16)(w >> 16));
        Y = fmaf(__expf(la), Y, bb);
        S += la;
      }
      int ci = (batch * NC2_ + c0 + ss) * D_ + d;
      carA[ci] = __expf(S);
      carY[ci] = Y;
    }
  }
}

// ------------------------------------- K3: scan carries, emit hin + h_last
__global__ __launch_bounds__(256) void k3_scan_carries(const float* __restrict__ carA,
                                                       const float* __restrict__ carY,
                                                       float* __restrict__ hin,
                                                       float* __restrict__ hlast){
  const int g = blockIdx.x * 256 + threadIdx.x;   // 0..4095 channels
  const int batch = g >> 10, d = g & 1023;
  float hcur = 0.0f;
  #pragma unroll 8
  for (int c = 0; c < NC2_; ++c){
    int ci = (batch * NC2_ + c) * D_ + d;
    float A = carA[ci], Y = carY[ci];
    hin[ci] = hcur;                  // state entering chunk c
    hcur = fmaf(A, hcur, Y);
  }
  hlast[batch * D_ + d] = hcur;      // == y[:, -1, :]
}

// --------------------------------- K2b: final scan; in-place pack -> y
// pack aliases y (same d_out region); per element the u32 read precedes the
// f32 write in the same thread. 2 channels/thread, float2 stores.
__global__ __launch_bounds__(256) void k2b_scan(const u32* pack,
                                                const float* __restrict__ hin,
                                                float* y_out){
  const int blk = blockIdx.x;
  const int cg = blk >> 1;           // 0..1023 = batch*NC2_ + c
  const int half = blk & 1;
  const int batch = cg >> 8;
  const int c = cg & (NC2_ - 1);
  const int d0 = half * 512 + threadIdx.x * 2;
  size_t base = ((size_t)batch * T_ + c * CL2_) * D_ + d0;
  float2 h0 = *(const float2*)(&hin[(size_t)cg * D_ + d0]);
  float y0 = h0.x, y1 = h0.y;
  #pragma unroll
  for (int t = 0; t < CL2_; ++t){
    size_t idx = base + (size_t)t * D_;
    uint2 w = *(const uint2*)(&pack[idx]);
    float a0 = __expf(bf2f((u16)(w.x & 0xFFFFu)));
    float b0 = bf2f((u16)(w.x >> 16));
    float a1 = __expf(bf2f((u16)(w.y & 0xFFFFu)));
    float b1 = bf2f((u16)(w.y >> 16));
    y0 = fmaf(a0, y0, b0);
    y1 = fmaf(a1, y1, b1);
    float2 yv; yv.x = y0; yv.y = y1;
    *(float2*)(&y_out[idx]) = yv;
  }
}

extern "C" void kernel_launch(void* const* d_in, const int* in_sizes, int n_in,
                              void* d_out, int out_size, void* d_ws, size_t ws_size,
                              hipStream_t stream) {
  const float* x    = (const float*)d_in[0];
  const float* ap   = (const float*)d_in[1];
  const float* w_in = (const float*)d_in[2];
  const float* w_a  = (const float*)d_in[3];
  float* y = (float*)d_out;                       // 16,777,216 floats
  float* hlast = y + (size_t)B_ * T_ * D_;        // + 4096 floats
  u32* pack = (u32*)d_out;                        // packed (la,b) lives in y region

  char* ws = (char*)d_ws;
  u16*   wt   = (u16*)(ws);                       //    524,288 B
  float* carA = (float*)(ws + 524288);            //  4,194,304 B
  float* carY = (float*)(ws + 524288 + 4194304);  //  4,194,304 B
  float* hin  = (float*)(ws + 524288 + 8388608);  //  4,194,304 B  (total ~12.6 MB)

  k0_transpose<<<16, 256, 0, stream>>>(w_in, w_a, wt);
  k1_gemm<<<(M_ / 128) * H_ * 2, 256, 0, stream>>>(x, ap, wt, pack, carA, carY);
  k3_scan_carries<<<16, 256, 0, stream>>>(carA, carY, hin, hlast);
  k2b_scan<<<B_ * NC2_ * 2, 256, 0, stream>>>(pack, hin, y);
}

// Round 4
// 196.408 us; speedup vs baseline: 1.1834x; 1.1148x over previous
//
#include <hip/hip_runtime.h>

#define B_ 4
#define T_ 4096
#define D_ 1024
#define H_ 8
#define CL2_ 16            // scan chunk length
#define NC2_ (T_/CL2_)     // 256 chunks per sequence
#define M_ (B_*T_)         // 16384 flat rows

typedef unsigned short u16;
typedef unsigned int u32;
typedef __attribute__((ext_vector_type(8))) short s16x8;
typedef __attribute__((ext_vector_type(4))) float f32x4;

#define LOG2E 1.4426950408889634f

__device__ __forceinline__ float ex2(float x){
#if __has_builtin(__builtin_amdgcn_exp2f)
  return __builtin_amdgcn_exp2f(x);
#else
  return exp2f(x);
#endif
}
__device__ __forceinline__ float rcpf(float x){
#if __has_builtin(__builtin_amdgcn_rcpf)
  return __builtin_amdgcn_rcpf(x);
#else
  return __fdividef(1.0f, x);
#endif
}
__device__ __forceinline__ float bf2f(u16 u){
  union { u32 i; float f; } v; v.i = ((u32)u) << 16; return v.f;
}
__device__ __forceinline__ u16 f2bf(float f){       // RNE
  union { float f; u32 i; } v; v.f = f;
  u32 i = v.i;
  return (u16)((i + 0x7FFFu + ((i >> 16) & 1u)) >> 16);
}
__device__ __forceinline__ float sigf(float z){     // 1/(1+e^-z), raw hw ops
  return rcpf(1.0f + ex2(-LOG2E * z));
}

// ---------------------------------------------------------------- K0
// wt[(mat*8+h)][e][k] = bf16(w_mat[h][k][e])
__global__ __launch_bounds__(256) void k0_transpose(const float* __restrict__ w_in,
                                                    const float* __restrict__ w_a,
                                                    u16* __restrict__ wt){
  __shared__ float ls[128][132];
  const int blk = blockIdx.x;                       // mat*8+h
  const float* src = (blk < 8 ? w_in : w_a) + (size_t)(blk & 7) * 128 * 128;
  u16* dst = wt + (size_t)blk * 128 * 128;
  const int tid = threadIdx.x;
  const int r0 = tid >> 5;          // 0..7
  const int c0 = (tid & 31) * 4;    // 0..124
  #pragma unroll
  for (int it = 0; it < 16; ++it){
    int r = r0 + it * 8;
    *(float4*)(&ls[r][c0]) = *(const float4*)(src + r * 128 + c0);
  }
  __syncthreads();
  #pragma unroll
  for (int it = 0; it < 16; ++it){
    int e = r0 + it * 8;
    ushort4 u;
    u.x = f2bf(ls[c0 + 0][e]);
    u.y = f2bf(ls[c0 + 1][e]);
    u.z = f2bf(ls[c0 + 2][e]);
    u.w = f2bf(ls[c0 + 3][e]);
    *(ushort4*)(dst + e * 128 + c0) = u;
  }
}

// ------------------------------------------------- K1: MFMA GEMM + gates + chunk carries
// grid = 2048: h = blk&7, eh = (blk>>3)&1 (e-half of the head), mb = blk>>4.
// One __syncthreads total. Epilogue stores packed (la|b) straight from acc;
// per-16-row chunk carries via quad-butterfly shuffles (no LDS round trip).
__global__ __launch_bounds__(256, 3) void k1_gemm(const float* __restrict__ x,
                                                  const float* __restrict__ a_param,
                                                  const u16* __restrict__ wt,
                                                  u32* __restrict__ pack,
                                                  float* __restrict__ carA,
                                                  float* __restrict__ carY){
  __shared__ u16 Xs[128][132];
  __shared__ float aspS[64];

  const int blk = blockIdx.x;
  const int h = blk & 7;
  const int eh = (blk >> 3) & 1;
  const int mbase = (blk >> 4) * 128;
  const int tid = threadIdx.x;

  // stage X tile (full K=128 of this head), fp32 -> bf16 (truncation: 1 op/el)
  {
    const int r0 = tid >> 5;          // 0..7
    const int c0 = (tid & 31) * 4;    // 0..124
    const float* xb = x + (size_t)mbase * D_ + h * 128;
    #pragma unroll
    for (int it = 0; it < 16; ++it){
      int r = r0 + it * 8;
      float4 v = *(const float4*)(xb + r * D_ + c0);
      ushort4 u;
      u.x = (u16)(__float_as_uint(v.x) >> 16);
      u.y = (u16)(__float_as_uint(v.y) >> 16);
      u.z = (u16)(__float_as_uint(v.z) >> 16);
      u.w = (u16)(__float_as_uint(v.w) >> 16);
      *(ushort4*)(&Xs[r][c0]) = u;
    }
  }
  if (tid < 64){
    float ap = a_param[h * 128 + eh * 64 + tid];
    aspS[tid] = 8.0f * log1pf(__expf(ap));   // C * softplus(a_param)
  }
  __syncthreads();

  const int wv = tid >> 6, lane = tid & 63;
  const int q = lane >> 4, l = lane & 15;

  f32x4 accX[2][4], accA[2][4];
  #pragma unroll
  for (int mt = 0; mt < 2; ++mt)
    #pragma unroll
    for (int nt = 0; nt < 4; ++nt){ accX[mt][nt] = (f32x4)0.0f; accA[mt][nt] = (f32x4)0.0f; }

  // B-frag rows: e = eh*64 + nt*16 + l ; second matrix at +8*128*128 elements.
  const u16* wbase = wt + (h * 128 + eh * 64 + l) * 128;
  #pragma unroll
  for (int kb = 0; kb < 4; ++kb){
    const int ko = kb * 32 + q * 8;
    s16x8 a0 = *(const s16x8*)(&Xs[wv * 32 + l][ko]);
    s16x8 a1 = *(const s16x8*)(&Xs[wv * 32 + 16 + l][ko]);
    #pragma unroll
    for (int nt = 0; nt < 4; ++nt){
      s16x8 bi = *(const s16x8*)(wbase + nt * 16 * 128 + ko);
      s16x8 ba = *(const s16x8*)(wbase + nt * 16 * 128 + ko + 8 * 128 * 128);
      accX[0][nt] = __builtin_amdgcn_mfma_f32_16x16x32_bf16(a0, bi, accX[0][nt], 0, 0, 0);
      accX[1][nt] = __builtin_amdgcn_mfma_f32_16x16x32_bf16(a1, bi, accX[1][nt], 0, 0, 0);
      accA[0][nt] = __builtin_amdgcn_mfma_f32_16x16x32_bf16(a0, ba, accA[0][nt], 0, 0, 0);
      accA[1][nt] = __builtin_amdgcn_mfma_f32_16x16x32_bf16(a1, ba, accA[1][nt], 0, 0, 0);
    }
  }

  // Epilogue. C/D layout: col=lane&15, row=(lane>>4)*4+reg  [m89/m91 verified]
  const int batch = mbase >> 12;                    // /T_
  const int cwb = ((mbase & (T_ - 1)) >> 4) + wv * 2;  // chunk within batch
  #pragma unroll
  for (int mt = 0; mt < 2; ++mt){
    const int R0 = wv * 32 + mt * 16;               // 16-row block == one chunk
    #pragma unroll
    for (int nt = 0; nt < 4; ++nt){
      const int el = nt * 16 + l;                   // within e-half
      const int col = eh * 64 + el;                 // Xs column (within head)
      const float asp = aspS[el];
      float av[4], bvv[4];
      #pragma unroll
      for (int r = 0; r < 4; ++r){
        const int row = R0 + q * 4 + r;
        float gx = sigf(accX[mt][nt][r]);
        float ga = sigf(accA[mt][nt][r]);
        float la = -asp * ga;                       // (-0.105, 0)
        float a  = ex2(LOG2E * la);
        float mult = sqrtf(fmaxf(1.0f - a * a, 0.0f));   // sqrt(1-exp(2la))
        float xv = bf2f(Xs[row][col]);
        float bv = mult * gx * xv;
        av[r] = a; bvv[r] = bv;
        pack[(mbase + row) * D_ + h * 128 + col] =
            (u32)f2bf(la) | ((u32)f2bf(bv) << 16);
      }
      // local 4-row carry, then butterfly across quads (ordered combine)
      float A = av[0] * av[1] * av[2] * av[3];
      float Y = bvv[0];
      Y = fmaf(av[1], Y, bvv[1]);
      Y = fmaf(av[2], Y, bvv[2]);
      Y = fmaf(av[3], Y, bvv[3]);
      float Ap = __shfl_xor(A, 16, 64);
      float Yp = __shfl_xor(Y, 16, 64);
      Y = (lane & 16) ? fmaf(A, Yp, Y) : fmaf(Ap, Y, Yp);
      A *= Ap;
      Ap = __shfl_xor(A, 32, 64);
      Yp = __shfl_xor(Y, 32, 64);
      Y = (lane & 32) ? fmaf(A, Yp, Y) : fmaf(Ap, Y, Yp);
      A *= Ap;
      if ((lane & 48) == 0){
        int ci = (batch * NC2_ + cwb + mt) * D_ + h * 128 + eh * 64 + nt * 16 + l;
        carA[ci] = A;
        carY[ci] = Y;
      }
    }
  }
}

// ------------------------------------- K3: scan carries, emit hin + h_last
__global__ __launch_bounds__(256) void k3_scan_carries(const float* __restrict__ carA,
                                                       const float* __restrict__ carY,
                                                       float* __restrict__ hin,
                                                       float* __restrict__ hlast){
  const int g = blockIdx.x * 256 + threadIdx.x;   // 0..4095 channels
  const int batch = g >> 10, d = g & 1023;
  float hcur = 0.0f;
  #pragma unroll 16
  for (int c = 0; c < NC2_; ++c){
    int ci = (batch * NC2_ + c) * D_ + d;
    float A = carA[ci], Y = carY[ci];
    hin[ci] = hcur;                  // state entering chunk c
    hcur = fmaf(A, hcur, Y);
  }
  hlast[batch * D_ + d] = hcur;      // == y[:, -1, :]
}

// --------------------------------- K2b: final scan; in-place pack -> y
// pack aliases y_out (both d_out): per element the uint4 read precedes the
// float4 write in the same thread -> safe. 4 channels/thread.
__global__ __launch_bounds__(256) void k2b_scan(const u32* pack,
                                               const float* __restrict__ hin,
                                               float* y_out){
  const int cg = blockIdx.x;          // batch*NC2_ + c, 0..1023
  const int d0 = threadIdx.x * 4;
  const int base = cg * (CL2_ * D_) + d0;
  float4 yv = *(const float4*)(&hin[cg * D_ + d0]);
  #pragma unroll
  for (int t = 0; t < CL2_; ++t){
    int idx = base + t * D_;
    uint4 w = *(const uint4*)(&pack[idx]);
    float a0 = ex2(LOG2E * bf2f((u16)(w.x & 0xFFFFu)));
    float a1 = ex2(LOG2E * bf2f((u16)(w.y & 0xFFFFu)));
    float a2 = ex2(LOG2E * bf2f((u16)(w.z & 0xFFFFu)));
    float a3 = ex2(LOG2E * bf2f((u16)(w.w & 0xFFFFu)));
    yv.x = fmaf(a0, yv.x, bf2f((u16)(w.x >> 16)));
    yv.y = fmaf(a1, yv.y, bf2f((u16)(w.y >> 16)));
    yv.z = fmaf(a2, yv.z, bf2f((u16)(w.z >> 16)));
    yv.w = fmaf(a3, yv.w, bf2f((u16)(w.w >> 16)));
    *(float4*)(&y_out[idx]) = yv;
  }
}

extern "C" void kernel_launch(void* const* d_in, const int* in_sizes, int n_in,
                              void* d_out, int out_size, void* d_ws, size_t ws_size,
                              hipStream_t stream) {
  const float* x    = (const float*)d_in[0];
  const float* ap   = (const float*)d_in[1];
  const float* w_in = (const float*)d_in[2];
  const float* w_a  = (const float*)d_in[3];
  float* y = (float*)d_out;                       // 16,777,216 floats
  float* hlast = y + (size_t)B_ * T_ * D_;        // + 4096 floats
  u32* pack = (u32*)d_out;                        // packed (la,b) lives in y region

  char* ws = (char*)d_ws;
  u16*   wt   = (u16*)(ws);                       //    524,288 B
  float* carA = (float*)(ws + 524288);            //  4,194,304 B
  float* carY = (float*)(ws + 524288 + 4194304);  //  4,194,304 B
  float* hin  = (float*)(ws + 524288 + 8388608);  //  4,194,304 B  (total ~12.6 MB)

  k0_transpose<<<16, 256, 0, stream>>>(w_in, w_a, wt);
  k1_gemm<<<(M_ / 128) * H_ * 2, 256, 0, stream>>>(x, ap, wt, pack, carA, carY);
  k3_scan_carries<<<16, 256, 0, stream>>>(carA, carY, hin, hlast);
  k2b_scan<<<B_ * NC2_, 256, 0, stream>>>(pack, hin, y);
}

// Round 5
// 185.560 us; speedup vs baseline: 1.2525x; 1.0585x over previous
//
#include <hip/hip_runtime.h>

#define B_ 4
#define T_ 4096
#define D_ 1024
#define H_ 8
#define CL2_ 16            // scan chunk length
#define NC2_ (T_/CL2_)     // 256 chunks per sequence
#define M_ (B_*T_)         // 16384 flat rows

typedef unsigned short u16;
typedef unsigned int u32;
typedef __attribute__((ext_vector_type(8))) short s16x8;
typedef __attribute__((ext_vector_type(4))) float f32x4;

#define LOG2E 1.4426950408889634f

__device__ __forceinline__ float ex2(float x){
#if __has_builtin(__builtin_amdgcn_exp2f)
  return __builtin_amdgcn_exp2f(x);
#else
  return exp2f(x);
#endif
}
__device__ __forceinline__ float rcpf(float x){
#if __has_builtin(__builtin_amdgcn_rcpf)
  return __builtin_amdgcn_rcpf(x);
#else
  return __fdividef(1.0f, x);
#endif
}
__device__ __forceinline__ float bf2f(u16 u){
  union { u32 i; float f; } v; v.i = ((u32)u) << 16; return v.f;
}
__device__ __forceinline__ u16 f2bf(float f){       // RNE
  union { float f; u32 i; } v; v.f = f;
  u32 i = v.i;
  return (u16)((i + 0x7FFFu + ((i >> 16) & 1u)) >> 16);
}
__device__ __forceinline__ float sigf(float z){     // 1/(1+e^-z), raw hw ops
  return rcpf(1.0f + ex2(-LOG2E * z));
}
__device__ __forceinline__ s16x8 cvt8(float4 a, float4 b){  // fp32x8 -> bf16x8 (trunc)
  s16x8 r;
  r[0] = (short)(__float_as_uint(a.x) >> 16);
  r[1] = (short)(__float_as_uint(a.y) >> 16);
  r[2] = (short)(__float_as_uint(a.z) >> 16);
  r[3] = (short)(__float_as_uint(a.w) >> 16);
  r[4] = (short)(__float_as_uint(b.x) >> 16);
  r[5] = (short)(__float_as_uint(b.y) >> 16);
  r[6] = (short)(__float_as_uint(b.z) >> 16);
  r[7] = (short)(__float_as_uint(b.w) >> 16);
  return r;
}

// ---------------------------------------------------------------- K0
// wt[(mat*8+h)][e][k] = bf16(w_mat[h][k][e])
__global__ __launch_bounds__(256) void k0_transpose(const float* __restrict__ w_in,
                                                    const float* __restrict__ w_a,
                                                    u16* __restrict__ wt){
  __shared__ float ls[128][132];
  const int blk = blockIdx.x;                       // mat*8+h
  const float* src = (blk < 8 ? w_in : w_a) + (size_t)(blk & 7) * 128 * 128;
  u16* dst = wt + (size_t)blk * 128 * 128;
  const int tid = threadIdx.x;
  const int r0 = tid >> 5;          // 0..7
  const int c0 = (tid & 31) * 4;    // 0..124
  #pragma unroll
  for (int it = 0; it < 16; ++it){
    int r = r0 + it * 8;
    *(float4*)(&ls[r][c0]) = *(const float4*)(src + r * 128 + c0);
  }
  __syncthreads();
  #pragma unroll
  for (int it = 0; it < 16; ++it){
    int e = r0 + it * 8;
    ushort4 u;
    u.x = f2bf(ls[c0 + 0][e]);
    u.y = f2bf(ls[c0 + 1][e]);
    u.z = f2bf(ls[c0 + 2][e]);
    u.w = f2bf(ls[c0 + 3][e]);
    *(ushort4*)(dst + e * 128 + c0) = u;
  }
}

// ------------------------------------------------- K1: MFMA GEMM + gates + chunk carries
// grid = 2048: h = blk&7, eh = (blk>>3)&1, mb = blk>>4 (128 rows).
// MLP-first structure: W tile staged to padded LDS (8 loads then 8 stores);
// A-fragments prefetched as 16 in-flight float4 from global, cvt in-register.
// Epilogue identical to R4 (scattered pack stores + shuffle carries).
__global__ __launch_bounds__(256, 2) void k1_gemm(const float* __restrict__ x,
                                                  const float* __restrict__ a_param,
                                                  const u16* __restrict__ wt,
                                                  u32* __restrict__ pack,
                                                  float* __restrict__ carA,
                                                  float* __restrict__ carY){
  __shared__ u16 wtS[2][64][136];    // +8 pad -> 2-way-free banking on b128 reads
  __shared__ float aspS[64];

  const int blk = blockIdx.x;
  const int h = blk & 7;
  const int eh = (blk >> 3) & 1;
  const int mbase = (blk >> 4) * 128;
  const int tid = threadIdx.x;
  const int wv = tid >> 6, lane = tid & 63;
  const int q = lane >> 4, l = lane & 15;

  // ---- stage both W tiles (32 KB): issue all 8 loads, then all 8 LDS writes
  {
    uint4 wbuf[8];
    #pragma unroll
    for (int it = 0; it < 8; ++it){
      int idx = tid + it * 256;          // 0..2047
      int row = idx >> 4;                // mat*64 + e
      int mat = row >> 6, e = row & 63;
      int c8 = (idx & 15) * 8;
      wbuf[it] = *(const uint4*)(wt + (size_t)mat * (8 * 128 * 128)
                                  + (h * 128 + eh * 64 + e) * 128 + c8);
    }
    #pragma unroll
    for (int it = 0; it < 8; ++it){
      int idx = tid + it * 256;
      int row = idx >> 4;
      int c8 = (idx & 15) * 8;
      *(uint4*)(&wtS[0][0][0] + row * 136 + c8) = wbuf[it];
    }
  }

  // ---- prefetch all A fragments (16 float4 in flight)
  const float* xr0 = x + (size_t)(mbase + wv * 32 + l) * D_ + h * 128;
  const float* xr1 = xr0 + 16 * D_;
  float4 A0[4][2], A1[4][2];
  #pragma unroll
  for (int kb = 0; kb < 4; ++kb){
    int ko = kb * 32 + q * 8;
    A0[kb][0] = *(const float4*)(xr0 + ko);
    A0[kb][1] = *(const float4*)(xr0 + ko + 4);
    A1[kb][0] = *(const float4*)(xr1 + ko);
    A1[kb][1] = *(const float4*)(xr1 + ko + 4);
  }

  if (tid < 64){
    float ap = a_param[h * 128 + eh * 64 + tid];
    aspS[tid] = 8.0f * log1pf(__expf(ap));   // C * softplus(a_param)
  }
  __syncthreads();

  f32x4 accX[2][4], accA[2][4];
  #pragma unroll
  for (int mt = 0; mt < 2; ++mt)
    #pragma unroll
    for (int nt = 0; nt < 4; ++nt){ accX[mt][nt] = (f32x4)0.0f; accA[mt][nt] = (f32x4)0.0f; }

  #pragma unroll
  for (int kb = 0; kb < 4; ++kb){
    const int ko = kb * 32 + q * 8;
    s16x8 a0 = cvt8(A0[kb][0], A0[kb][1]);
    s16x8 a1 = cvt8(A1[kb][0], A1[kb][1]);
    #pragma unroll
    for (int nt = 0; nt < 4; ++nt){
      s16x8 bi = *(const s16x8*)(&wtS[0][nt * 16 + l][ko]);
      s16x8 ba = *(const s16x8*)(&wtS[1][nt * 16 + l][ko]);
      accX[0][nt] = __builtin_amdgcn_mfma_f32_16x16x32_bf16(a0, bi, accX[0][nt], 0, 0, 0);
      accX[1][nt] = __builtin_amdgcn_mfma_f32_16x16x32_bf16(a1, bi, accX[1][nt], 0, 0, 0);
      accA[0][nt] = __builtin_amdgcn_mfma_f32_16x16x32_bf16(a0, ba, accA[0][nt], 0, 0, 0);
      accA[1][nt] = __builtin_amdgcn_mfma_f32_16x16x32_bf16(a1, ba, accA[1][nt], 0, 0, 0);
    }
  }

  // Epilogue. C/D layout: col=lane&15, row=(lane>>4)*4+reg  [m89/m91 verified]
  const int batch = mbase >> 12;                    // /T_
  const int cwb = ((mbase & (T_ - 1)) >> 4) + wv * 2;  // chunk within batch
  #pragma unroll
  for (int mt = 0; mt < 2; ++mt){
    const int R0 = wv * 32 + mt * 16;               // 16-row block == one chunk
    #pragma unroll
    for (int nt = 0; nt < 4; ++nt){
      const int el = nt * 16 + l;                   // within e-half
      const int col = eh * 64 + el;                 // within head
      const float asp = aspS[el];
      float av[4], bvv[4];
      #pragma unroll
      for (int r = 0; r < 4; ++r){
        const int row = R0 + q * 4 + r;
        float gx = sigf(accX[mt][nt][r]);
        float ga = sigf(accA[mt][nt][r]);
        float la = -asp * ga;                       // (-0.105, 0)
        float a  = ex2(LOG2E * la);
        float mult = sqrtf(fmaxf(1.0f - a * a, 0.0f));   // sqrt(1-exp(2la))
        float xv = x[(size_t)(mbase + row) * D_ + h * 128 + col];
        float bv = mult * gx * xv;
        av[r] = a; bvv[r] = bv;
        pack[(mbase + row) * D_ + h * 128 + col] =
            (u32)f2bf(la) | ((u32)f2bf(bv) << 16);
      }
      // local 4-row carry, then butterfly across quads (ordered combine)
      float A = av[0] * av[1] * av[2] * av[3];
      float Y = bvv[0];
      Y = fmaf(av[1], Y, bvv[1]);
      Y = fmaf(av[2], Y, bvv[2]);
      Y = fmaf(av[3], Y, bvv[3]);
      float Ap = __shfl_xor(A, 16, 64);
      float Yp = __shfl_xor(Y, 16, 64);
      Y = (lane & 16) ? fmaf(A, Yp, Y) : fmaf(Ap, Y, Yp);
      A *= Ap;
      Ap = __shfl_xor(A, 32, 64);
      Yp = __shfl_xor(Y, 32, 64);
      Y = (lane & 32) ? fmaf(A, Yp, Y) : fmaf(Ap, Y, Yp);
      A *= Ap;
      if ((lane & 48) == 0){
        int ci = (batch * NC2_ + cwb + mt) * D_ + h * 128 + eh * 64 + nt * 16 + l;
        carA[ci] = A;
        carY[ci] = Y;
      }
    }
  }
}

// ------------------------------------- K3: scan carries, emit hin + h_last
__global__ __launch_bounds__(256) void k3_scan_carries(const float* __restrict__ carA,
                                                       const float* __restrict__ carY,
                                                       float* __restrict__ hin,
                                                       float* __restrict__ hlast){
  const int g = blockIdx.x * 256 + threadIdx.x;   // 0..4095 channels
  const int batch = g >> 10, d = g & 1023;
  float hcur = 0.0f;
  #pragma unroll 16
  for (int c = 0; c < NC2_; ++c){
    int ci = (batch * NC2_ + c) * D_ + d;
    float A = carA[ci], Y = carY[ci];
    hin[ci] = hcur;                  // state entering chunk c
    hcur = fmaf(A, hcur, Y);
  }
  hlast[batch * D_ + d] = hcur;      // == y[:, -1, :]
}

// --------------------------------- K2b: final scan; in-place pack -> y
__global__ __launch_bounds__(256) void k2b_scan(const u32* pack,
                                               const float* __restrict__ hin,
                                               float* y_out){
  const int cg = blockIdx.x;          // batch*NC2_ + c, 0..1023
  const int d0 = threadIdx.x * 4;
  const int base = cg * (CL2_ * D_) + d0;
  float4 yv = *(const float4*)(&hin[cg * D_ + d0]);
  #pragma unroll
  for (int t = 0; t < CL2_; ++t){
    int idx = base + t * D_;
    uint4 w = *(const uint4*)(&pack[idx]);
    float a0 = ex2(LOG2E * bf2f((u16)(w.x & 0xFFFFu)));
    float a1 = ex2(LOG2E * bf2f((u16)(w.y & 0xFFFFu)));
    float a2 = ex2(LOG2E * bf2f((u16)(w.z & 0xFFFFu)));
    float a3 = ex2(LOG2E * bf2f((u16)(w.w & 0xFFFFu)));
    yv.x = fmaf(a0, yv.x, bf2f((u16)(w.x >> 16)));
    yv.y = fmaf(a1, yv.y, bf2f((u16)(w.y >> 16)));
    yv.z = fmaf(a2, yv.z, bf2f((u16)(w.z >> 16)));
    yv.w = fmaf(a3, yv.w, bf2f((u16)(w.w >> 16)));
    *(float4*)(&y_out[idx]) = yv;
  }
}

extern "C" void kernel_launch(void* const* d_in, const int* in_sizes, int n_in,
                              void* d_out, int out_size, void* d_ws, size_t ws_size,
                              hipStream_t stream) {
  const float* x    = (const float*)d_in[0];
  const float* ap   = (const float*)d_in[1];
  const float* w_in = (const float*)d_in[2];
  const float* w_a  = (const float*)d_in[3];
  float* y = (float*)d_out;                       // 16,777,216 floats
  float* hlast = y + (size_t)B_ * T_ * D_;        // + 4096 floats
  u32* pack = (u32*)d_out;                        // packed (la,b) lives in y region

  char* ws = (char*)d_ws;
  u16*   wt   = (u16*)(ws);                       //    524,288 B
  float* carA = (float*)(ws + 524288);            //  4,194,304 B
  float* carY = (float*)(ws + 524288 + 4194304);  //  4,194,304 B
  float* hin  = (float*)(ws + 524288 + 8388608);  //  4,194,304 B  (total ~12.6 MB)

  k0_transpose<<<16, 256, 0, stream>>>(w_in, w_a, wt);
  k1_gemm<<<(M_ / 128) * H_ * 2, 256, 0, stream>>>(x, ap, wt, pack, carA, carY);
  k3_scan_carries<<<16, 256, 0, stream>>>(carA, carY, hin, hlast);
  k2b_scan<<<B_ * NC2_, 256, 0, stream>>>(pack, hin, y);
}